// Round 7
// baseline (57.196 us; speedup 1.0000x reference)
//
#include <hip/hip_runtime.h>
#include <math.h>

#define SIZE 1024
#define BATCH 32
#define SEQ 2048
#define PARTS 16         // e-dim split within a block
#define EPART (SIZE / PARTS)

// ---------------------------------------------------------------------------
// Kernel 1 (fused project+reduce): v[b][d] = sum_e dh[b,e] * W[e,d]
// One block per (b, 64-column chunk): 512 blocks x 256 threads; LDS tree
// reduction over the 16 e-parts. (Round-6 verified, ~0.7us win vs split.)
// ---------------------------------------------------------------------------
__global__ __launch_bounds__(256) void k_project(const float* __restrict__ dh,
                                                 const float* __restrict__ W,
                                                 float* __restrict__ v) {
    int bid    = blockIdx.x;        // 0..511
    int b      = bid >> 4;          // 0..31
    int dchunk = bid & 15;          // 0..15
    int tid    = threadIdx.x;
    int p      = tid >> 4;          // 0..15 (e-part)
    int d4l    = tid & 15;          // 0..15
    int d4     = dchunk * 16 + d4l; // 0..255 (float4 column)

    const float4* W4  = (const float4*)W;          // [SIZE][SIZE/4]
    const float*  dhb = dh + b * SIZE;

    float4 acc = make_float4(0.f, 0.f, 0.f, 0.f);
    int e0 = p * EPART;
    #pragma unroll 8
    for (int e = e0; e < e0 + EPART; ++e) {
        float  s = dhb[e];                         // 16-lane broadcast load
        float4 w = W4[e * (SIZE / 4) + d4];
        acc.x += s * w.x;
        acc.y += s * w.y;
        acc.z += s * w.z;
        acc.w += s * w.w;
    }

    __shared__ float4 red[256];                    // [p][d4l], 4KB
    red[tid] = acc;
    __syncthreads();
    #pragma unroll
    for (int stride = 128; stride >= 16; stride >>= 1) {
        if (tid < stride) {
            float4 o = red[tid + stride];
            float4 a = red[tid];
            a.x += o.x; a.y += o.y; a.z += o.z; a.w += o.w;
            red[tid] = a;
        }
        __syncthreads();
    }
    if (tid < 16)
        ((float4*)v)[b * (SIZE / 4) + dchunk * 16 + tid] = red[tid];
}

// ---------------------------------------------------------------------------
// Kernel 2: energies[b][s] = v[b] . enc[s][b][:]
// 2 s-rows per wave (measured sweet spot: 1-row=61.7, 2-row=56.0, 4-row=61.9).
// Round-7 deltas: (a) v hoisted into registers before the k-loop -- per-iter
// loads drop 12->8, all enc-stream; (b) 512-thread blocks (8 waves) -> 4096
// workgroups. Carries the 268 MB HBM read; plain cached loads (nt = 25x
// regression in round 3).
// ---------------------------------------------------------------------------
__global__ __launch_bounds__(512) void k_energies(const float* __restrict__ enc,
                                                  const float* __restrict__ v,
                                                  float* __restrict__ energies) {
    int wave = blockIdx.x * 8 + (threadIdx.x >> 6);  // 0..32767
    int lane = threadIdx.x & 63;
    int b  = wave & 31;                              // 0..31
    int sp = wave >> 5;                              // 0..1023 (s-pair)
    size_t s0 = (size_t)sp * 2;

    const float4* row0 = (const float4*)(enc + (s0 * BATCH + b) * SIZE);
    const float4* row1 = (const float4*)(enc + ((s0 + 1) * BATCH + b) * SIZE);
    const float4* vb   = (const float4*)(v + b * SIZE);

    // v operand: 4 float4 per lane, loaded ONCE (L1/L2-resident, shared by
    // all waves of the same b).
    float4 vv0 = vb[lane];
    float4 vv1 = vb[lane + 64];
    float4 vv2 = vb[lane + 128];
    float4 vv3 = vb[lane + 192];

    float a0 = 0.f, a1 = 0.f;
    {
        float4 e0 = row0[lane];
        float4 e1 = row1[lane];
        a0 += e0.x * vv0.x + e0.y * vv0.y + e0.z * vv0.z + e0.w * vv0.w;
        a1 += e1.x * vv0.x + e1.y * vv0.y + e1.z * vv0.z + e1.w * vv0.w;
    }
    {
        float4 e0 = row0[lane + 64];
        float4 e1 = row1[lane + 64];
        a0 += e0.x * vv1.x + e0.y * vv1.y + e0.z * vv1.z + e0.w * vv1.w;
        a1 += e1.x * vv1.x + e1.y * vv1.y + e1.z * vv1.z + e1.w * vv1.w;
    }
    {
        float4 e0 = row0[lane + 128];
        float4 e1 = row1[lane + 128];
        a0 += e0.x * vv2.x + e0.y * vv2.y + e0.z * vv2.z + e0.w * vv2.w;
        a1 += e1.x * vv2.x + e1.y * vv2.y + e1.z * vv2.z + e1.w * vv2.w;
    }
    {
        float4 e0 = row0[lane + 192];
        float4 e1 = row1[lane + 192];
        a0 += e0.x * vv3.x + e0.y * vv3.y + e0.z * vv3.z + e0.w * vv3.w;
        a1 += e1.x * vv3.x + e1.y * vv3.y + e1.z * vv3.z + e1.w * vv3.w;
    }

    #pragma unroll
    for (int off = 32; off; off >>= 1) {
        a0 += __shfl_down(a0, off, 64);
        a1 += __shfl_down(a1, off, 64);
    }
    if (lane == 0)
        ((float2*)(energies + b * SEQ))[sp] = make_float2(a0, a1);
}

// ---------------------------------------------------------------------------
// Kernel 3: row softmax over s. One block per b; 256 threads x 8 elems each.
// Bias term is constant over s and cancels under softmax shift invariance.
// ---------------------------------------------------------------------------
__global__ __launch_bounds__(256) void k_softmax(const float* __restrict__ energies,
                                                 float* __restrict__ out) {
    int b = blockIdx.x;
    const float* row = energies + b * SEQ;
    int t = threadIdx.x;
    int wid = t >> 6, lane = t & 63;

    float vals[8];
    float m = -INFINITY;
    #pragma unroll
    for (int i = 0; i < 8; ++i) {
        vals[i] = row[t + (i << 8)];
        m = fmaxf(m, vals[i]);
    }
    __shared__ float redm[4];
    #pragma unroll
    for (int off = 32; off; off >>= 1) m = fmaxf(m, __shfl_down(m, off, 64));
    if (lane == 0) redm[wid] = m;
    __syncthreads();
    m = fmaxf(fmaxf(redm[0], redm[1]), fmaxf(redm[2], redm[3]));

    float sum = 0.f;
    #pragma unroll
    for (int i = 0; i < 8; ++i) {
        vals[i] = __expf(vals[i] - m);
        sum += vals[i];
    }
    __shared__ float reds[4];
    #pragma unroll
    for (int off = 32; off; off >>= 1) sum += __shfl_down(sum, off, 64);
    if (lane == 0) reds[wid] = sum;
    __syncthreads();
    sum = reds[0] + reds[1] + reds[2] + reds[3];

    float inv = 1.f / sum;
    #pragma unroll
    for (int i = 0; i < 8; ++i)
        out[b * SEQ + t + (i << 8)] = vals[i] * inv;
}

// ---------------------------------------------------------------------------
extern "C" void kernel_launch(void* const* d_in, const int* in_sizes, int n_in,
                              void* d_out, int out_size, void* d_ws, size_t ws_size,
                              hipStream_t stream) {
    const float* dh  = (const float*)d_in[0];   // [32, 1024]
    const float* enc = (const float*)d_in[1];   // [2048, 32, 1024]
    const float* W   = (const float*)d_in[2];   // [1024, 1024]
    // d_in[3] = bias: unused (cancels under softmax shift invariance)

    float* ws       = (float*)d_ws;
    float* v        = ws;                                   // 32*1024 = 32768 f
    float* energies = v + BATCH * SIZE;                     // 32*2048 = 65536 f

    k_project <<<BATCH * 16, 256, 0, stream>>>(dh, W, v);
    k_energies<<<(BATCH * SEQ / 2) / 8, 512, 0, stream>>>(enc, v, energies);
    k_softmax <<<BATCH, 256, 0, stream>>>(energies, (float*)d_out);
}

// Round 8
// 55.710 us; speedup vs baseline: 1.0267x; 1.0267x over previous
//
#include <hip/hip_runtime.h>
#include <math.h>

#define SIZE 1024
#define BATCH 32
#define SEQ 2048
#define PARTS 16         // e-dim split within a block
#define EPART (SIZE / PARTS)

__device__ __forceinline__ float dot4(float4 a, float4 b) {
    return a.x * b.x + a.y * b.y + a.z * b.z + a.w * b.w;
}

// ---------------------------------------------------------------------------
// Kernel 1 (fused project+reduce): v[b][d] = sum_e dh[b,e] * W[e,d]
// One block per (b, 64-column chunk): 512 blocks x 256 threads; LDS tree
// reduction over the 16 e-parts. (Round-6 verified.)
// ---------------------------------------------------------------------------
__global__ __launch_bounds__(256) void k_project(const float* __restrict__ dh,
                                                 const float* __restrict__ W,
                                                 float* __restrict__ v) {
    int bid    = blockIdx.x;        // 0..511
    int b      = bid >> 4;          // 0..31
    int dchunk = bid & 15;          // 0..15
    int tid    = threadIdx.x;
    int p      = tid >> 4;          // 0..15 (e-part)
    int d4l    = tid & 15;          // 0..15
    int d4     = dchunk * 16 + d4l; // 0..255 (float4 column)

    const float4* W4  = (const float4*)W;          // [SIZE][SIZE/4]
    const float*  dhb = dh + b * SIZE;

    float4 acc = make_float4(0.f, 0.f, 0.f, 0.f);
    int e0 = p * EPART;
    #pragma unroll 8
    for (int e = e0; e < e0 + EPART; ++e) {
        float  s = dhb[e];                         // 16-lane broadcast load
        float4 w = W4[e * (SIZE / 4) + d4];
        acc.x += s * w.x;
        acc.y += s * w.y;
        acc.z += s * w.z;
        acc.w += s * w.w;
    }

    __shared__ float4 red[256];                    // [p][d4l], 4KB
    red[tid] = acc;
    __syncthreads();
    #pragma unroll
    for (int stride = 128; stride >= 16; stride >>= 1) {
        if (tid < stride) {
            float4 o = red[tid + stride];
            float4 a = red[tid];
            a.x += o.x; a.y += o.y; a.z += o.z; a.w += o.w;
            red[tid] = a;
        }
        __syncthreads();
    }
    if (tid < 16)
        ((float4*)v)[b * (SIZE / 4) + dchunk * 16 + tid] = red[tid];
}

// ---------------------------------------------------------------------------
// Kernel 2: energies[b][s] = v[b] . enc[s][b][:]
// Pipelined: each wave owns 4 s-pair items (stride 256 in sp-space, same b),
// double-buffered so item i+1's 8 stream loads are in flight during item i's
// dot+shuffle+store tail (waits become vmcnt(8), not vmcnt(0)). v loaded once
// per wave, amortized over 8 rows. 8192 waves = 2048 blocks x 256 threads;
// 4 consecutive b per block -> 16KB contiguous chunks per load phase.
// Carries the 268 MB HBM read; plain cached loads.
// ---------------------------------------------------------------------------
__global__ __launch_bounds__(256) void k_energies(const float* __restrict__ enc,
                                                  const float* __restrict__ v,
                                                  float* __restrict__ energies) {
    int wv   = blockIdx.x * 4 + (threadIdx.x >> 6);  // 0..8191
    int lane = threadIdx.x & 63;
    int b    = wv & 31;                              // 0..31 (same for all 4 items)
    int spb  = wv >> 5;                              // 0..255 base s-pair

    const float4* vb = (const float4*)(v + b * SIZE);
    float4 vv0 = vb[lane];
    float4 vv1 = vb[lane + 64];
    float4 vv2 = vb[lane + 128];
    float4 vv3 = vb[lane + 192];

    float4 c0, c1, c2, c3, c4, c5, c6, c7;           // current item buffers
    float4 n0, n1, n2, n3, n4, n5, n6, n7;           // next item buffers

    auto load = [&](int sp, float4& e0, float4& e1, float4& e2, float4& e3,
                    float4& e4, float4& e5, float4& e6, float4& e7) {
        size_t s0 = (size_t)sp * 2;
        const float4* r0 = (const float4*)(enc + (s0 * BATCH + b) * SIZE);
        const float4* r1 = (const float4*)(enc + ((s0 + 1) * BATCH + b) * SIZE);
        e0 = r0[lane];       e1 = r0[lane + 64];
        e2 = r0[lane + 128]; e3 = r0[lane + 192];
        e4 = r1[lane];       e5 = r1[lane + 64];
        e6 = r1[lane + 128]; e7 = r1[lane + 192];
    };
    auto compute_store = [&](int sp, float4 e0, float4 e1, float4 e2, float4 e3,
                             float4 e4, float4 e5, float4 e6, float4 e7) {
        float a0 = dot4(e0, vv0) + dot4(e1, vv1) + dot4(e2, vv2) + dot4(e3, vv3);
        float a1 = dot4(e4, vv0) + dot4(e5, vv1) + dot4(e6, vv2) + dot4(e7, vv3);
        #pragma unroll
        for (int off = 32; off; off >>= 1) {
            a0 += __shfl_down(a0, off, 64);
            a1 += __shfl_down(a1, off, 64);
        }
        if (lane == 0)
            ((float2*)(energies + b * SEQ))[sp] = make_float2(a0, a1);
    };

    // 4-item software pipeline, fully unrolled, static register buffers.
    load(spb,       c0, c1, c2, c3, c4, c5, c6, c7);
    load(spb + 256, n0, n1, n2, n3, n4, n5, n6, n7);
    compute_store(spb, c0, c1, c2, c3, c4, c5, c6, c7);
    load(spb + 512, c0, c1, c2, c3, c4, c5, c6, c7);
    compute_store(spb + 256, n0, n1, n2, n3, n4, n5, n6, n7);
    load(spb + 768, n0, n1, n2, n3, n4, n5, n6, n7);
    compute_store(spb + 512, c0, c1, c2, c3, c4, c5, c6, c7);
    compute_store(spb + 768, n0, n1, n2, n3, n4, n5, n6, n7);
}

// ---------------------------------------------------------------------------
// Kernel 3: row softmax over s. One block per b; 256 threads x 8 elems each.
// Bias term is constant over s and cancels under softmax shift invariance.
// ---------------------------------------------------------------------------
__global__ __launch_bounds__(256) void k_softmax(const float* __restrict__ energies,
                                                 float* __restrict__ out) {
    int b = blockIdx.x;
    const float* row = energies + b * SEQ;
    int t = threadIdx.x;
    int wid = t >> 6, lane = t & 63;

    float vals[8];
    float m = -INFINITY;
    #pragma unroll
    for (int i = 0; i < 8; ++i) {
        vals[i] = row[t + (i << 8)];
        m = fmaxf(m, vals[i]);
    }
    __shared__ float redm[4];
    #pragma unroll
    for (int off = 32; off; off >>= 1) m = fmaxf(m, __shfl_down(m, off, 64));
    if (lane == 0) redm[wid] = m;
    __syncthreads();
    m = fmaxf(fmaxf(redm[0], redm[1]), fmaxf(redm[2], redm[3]));

    float sum = 0.f;
    #pragma unroll
    for (int i = 0; i < 8; ++i) {
        vals[i] = __expf(vals[i] - m);
        sum += vals[i];
    }
    __shared__ float reds[4];
    #pragma unroll
    for (int off = 32; off; off >>= 1) sum += __shfl_down(sum, off, 64);
    if (lane == 0) reds[wid] = sum;
    __syncthreads();
    sum = reds[0] + reds[1] + reds[2] + reds[3];

    float inv = 1.f / sum;
    #pragma unroll
    for (int i = 0; i < 8; ++i)
        out[b * SEQ + t + (i << 8)] = vals[i] * inv;
}

// ---------------------------------------------------------------------------
extern "C" void kernel_launch(void* const* d_in, const int* in_sizes, int n_in,
                              void* d_out, int out_size, void* d_ws, size_t ws_size,
                              hipStream_t stream) {
    const float* dh  = (const float*)d_in[0];   // [32, 1024]
    const float* enc = (const float*)d_in[1];   // [2048, 32, 1024]
    const float* W   = (const float*)d_in[2];   // [1024, 1024]
    // d_in[3] = bias: unused (cancels under softmax shift invariance)

    float* ws       = (float*)d_ws;
    float* v        = ws;                                   // 32*1024 = 32768 f
    float* energies = v + BATCH * SIZE;                     // 32*2048 = 65536 f

    k_project <<<BATCH * 16, 256, 0, stream>>>(dh, W, v);
    k_energies<<<2048, 256, 0, stream>>>(enc, v, energies);
    k_softmax <<<BATCH, 256, 0, stream>>>(energies, (float*)d_out);
}

// Round 9
// 54.871 us; speedup vs baseline: 1.0424x; 1.0153x over previous
//
#include <hip/hip_runtime.h>
#include <math.h>

#define SIZE 1024
#define BATCH 32
#define SEQ 2048
#define PARTS 16         // e-dim split within a block
#define EPART (SIZE / PARTS)

// ---------------------------------------------------------------------------
// FINAL CONFIGURATION (best measured: 55.3 us, round 6).
//
// Algebra: energies[b,s] = dh[b]·(W·enc[s,b]+bias) = (dh[b]·W)·enc[s,b] + const(b);
// the const cancels under softmax shift invariance, and precomputing
// v[b] = dh[b]·W removes 99.95% of reference FLOPs. The problem is then a
// single irreducible 268 MB enc stream (~43 us at the 6.3 TB/s measured
// ceiling) + two tiny kernels + launch structure.
//
// Measured ladder: rows/wave 1/2/4 = 61.7/56.0/61.9; project+reduce LDS merge
// -0.7us; v-hoist+512t +1.9; SW pipeline +0.4; nt loads 25x toxic; cross-block
// ticket fusion 2.5-27x toxic. This file = the winning combination only.
// ---------------------------------------------------------------------------

// Kernel 1 (fused project+reduce): v[b][d] = sum_e dh[b,e] * W[e,d]
// One block per (b, 64-column chunk): 512 blocks x 256 threads; LDS tree
// reduction over the 16 e-parts.
__global__ __launch_bounds__(256) void k_project(const float* __restrict__ dh,
                                                 const float* __restrict__ W,
                                                 float* __restrict__ v) {
    int bid    = blockIdx.x;        // 0..511
    int b      = bid >> 4;          // 0..31
    int dchunk = bid & 15;          // 0..15
    int tid    = threadIdx.x;
    int p      = tid >> 4;          // 0..15 (e-part)
    int d4l    = tid & 15;          // 0..15
    int d4     = dchunk * 16 + d4l; // 0..255 (float4 column)

    const float4* W4  = (const float4*)W;          // [SIZE][SIZE/4]
    const float*  dhb = dh + b * SIZE;

    float4 acc = make_float4(0.f, 0.f, 0.f, 0.f);
    int e0 = p * EPART;
    #pragma unroll 8
    for (int e = e0; e < e0 + EPART; ++e) {
        float  s = dhb[e];                         // 16-lane broadcast load
        float4 w = W4[e * (SIZE / 4) + d4];
        acc.x += s * w.x;
        acc.y += s * w.y;
        acc.z += s * w.z;
        acc.w += s * w.w;
    }

    __shared__ float4 red[256];                    // [p][d4l], 4KB
    red[tid] = acc;
    __syncthreads();
    #pragma unroll
    for (int stride = 128; stride >= 16; stride >>= 1) {
        if (tid < stride) {
            float4 o = red[tid + stride];
            float4 a = red[tid];
            a.x += o.x; a.y += o.y; a.z += o.z; a.w += o.w;
            red[tid] = a;
        }
        __syncthreads();
    }
    if (tid < 16)
        ((float4*)v)[b * (SIZE / 4) + dchunk * 16 + tid] = red[tid];
}

// Kernel 2: energies[b][s] = v[b] . enc[s][b][:]
// One wave per (s-pair, b): 2 adjacent s rows share the v operand, 8
// independent 1KB enc loads in flight per wave (measured sweet spot).
// 32768 waves = 8192 blocks x 256. Carries the 268 MB HBM read at ~5.7 TB/s.
__global__ __launch_bounds__(256) void k_energies(const float* __restrict__ enc,
                                                  const float* __restrict__ v,
                                                  float* __restrict__ energies) {
    int wave = blockIdx.x * 4 + (threadIdx.x >> 6);  // 0..32767
    int lane = threadIdx.x & 63;
    int b  = wave & 31;                              // 0..31
    int sp = wave >> 5;                              // 0..1023 (s-pair)
    size_t s0 = (size_t)sp * 2;

    const float4* row0 = (const float4*)(enc + (s0 * BATCH + b) * SIZE);
    const float4* row1 = (const float4*)(enc + ((s0 + 1) * BATCH + b) * SIZE);
    const float4* vb   = (const float4*)(v + b * SIZE);

    float a0 = 0.f, a1 = 0.f;
    #pragma unroll
    for (int k = 0; k < 4; ++k) {
        int idx = lane + (k << 6);
        float4 e0 = row0[idx];
        float4 e1 = row1[idx];
        float4 vv = vb[idx];
        a0 += e0.x * vv.x + e0.y * vv.y + e0.z * vv.z + e0.w * vv.w;
        a1 += e1.x * vv.x + e1.y * vv.y + e1.z * vv.z + e1.w * vv.w;
    }
    #pragma unroll
    for (int off = 32; off; off >>= 1) {
        a0 += __shfl_down(a0, off, 64);
        a1 += __shfl_down(a1, off, 64);
    }
    if (lane == 0)
        ((float2*)(energies + b * SEQ))[sp] = make_float2(a0, a1);
}

// Kernel 3: row softmax over s. One block per b; 256 threads x 8 elems each.
// Bias term is constant over s and cancels under softmax shift invariance.
__global__ __launch_bounds__(256) void k_softmax(const float* __restrict__ energies,
                                                 float* __restrict__ out) {
    int b = blockIdx.x;
    const float* row = energies + b * SEQ;
    int t = threadIdx.x;
    int wid = t >> 6, lane = t & 63;

    float vals[8];
    float m = -INFINITY;
    #pragma unroll
    for (int i = 0; i < 8; ++i) {
        vals[i] = row[t + (i << 8)];
        m = fmaxf(m, vals[i]);
    }
    __shared__ float redm[4];
    #pragma unroll
    for (int off = 32; off; off >>= 1) m = fmaxf(m, __shfl_down(m, off, 64));
    if (lane == 0) redm[wid] = m;
    __syncthreads();
    m = fmaxf(fmaxf(redm[0], redm[1]), fmaxf(redm[2], redm[3]));

    float sum = 0.f;
    #pragma unroll
    for (int i = 0; i < 8; ++i) {
        vals[i] = __expf(vals[i] - m);
        sum += vals[i];
    }
    __shared__ float reds[4];
    #pragma unroll
    for (int off = 32; off; off >>= 1) sum += __shfl_down(sum, off, 64);
    if (lane == 0) reds[wid] = sum;
    __syncthreads();
    sum = reds[0] + reds[1] + reds[2] + reds[3];

    float inv = 1.f / sum;
    #pragma unroll
    for (int i = 0; i < 8; ++i)
        out[b * SEQ + t + (i << 8)] = vals[i] * inv;
}

// ---------------------------------------------------------------------------
extern "C" void kernel_launch(void* const* d_in, const int* in_sizes, int n_in,
                              void* d_out, int out_size, void* d_ws, size_t ws_size,
                              hipStream_t stream) {
    const float* dh  = (const float*)d_in[0];   // [32, 1024]
    const float* enc = (const float*)d_in[1];   // [2048, 32, 1024]
    const float* W   = (const float*)d_in[2];   // [1024, 1024]
    // d_in[3] = bias: unused (cancels under softmax shift invariance)

    float* ws       = (float*)d_ws;
    float* v        = ws;                                   // 32*1024 = 32768 f
    float* energies = v + BATCH * SIZE;                     // 32*2048 = 65536 f

    k_project <<<BATCH * 16, 256, 0, stream>>>(dh, W, v);
    k_energies<<<(BATCH * SEQ / 2) / 4, 256, 0, stream>>>(enc, v, energies);
    k_softmax <<<BATCH, 256, 0, stream>>>(energies, (float*)d_out);
}